// Round 5
// baseline (454.145 us; speedup 1.0000x reference)
//
#include <hip/hip_runtime.h>
#include <hip/hip_bf16.h>
#include <math.h>

#define D_MODEL    1024
#define EXPERT_DIM 4096
#define N_EXPERTS  8
#define N_TOKENS   4096
#define M_TILE     128
#define MAX_TILES  40
#define KSPLIT     4

typedef __attribute__((ext_vector_type(8))) short short8;
typedef __attribute__((ext_vector_type(4))) float f32x4;

// workspace byte offsets (R3 proved ws_size >= 176,422,912)
#define OFF_PROBS   0u
#define OFF_EXP     131072u
#define OFF_GATE    147456u
#define OFF_CNT     163840u     // 8 i32
#define OFF_CUR     163872u     // 8 i32
#define OFF_SIMP    163904u     // 8 f32
#define OFF_OFFS    163936u     // 9 i32
#define OFF_NT      163976u     // 1 i32
#define OFF_TE      164096u     // 40 i32
#define OFF_TR      164352u     // 40 i32
#define OFF_BUCKET  164608u     // 4096 i32
#define OFF_XB      262144u     // 4096*1024 bf16 = 8 MiB
#define OFF_H       8650752u    // 4096*4096 bf16 = 32 MiB (ends ~40.3 MiB)
#define OFF_P       42205184u   // KSPLIT*4096*1024 f32 = 64 MiB (ends ~106 MiB)

#define GLOAD_LDS16(gp, lp) \
  __builtin_amdgcn_global_load_lds((const __attribute__((address_space(1))) void*)(gp), \
                                   (__attribute__((address_space(3))) void*)(lp), 16, 0, 0)

static __device__ __forceinline__ ushort f2b(float f) {
  union { __hip_bfloat16 h; ushort u; } c;
  c.h = __float2bfloat16(f);
  return c.u;
}
static __device__ __forceinline__ float b2f(ushort u) {
  union { unsigned int i; float f; } c;
  c.i = ((unsigned int)u) << 16;
  return c.f;
}

static __device__ __forceinline__ short8 pack8(float4 a, float4 b) {
  short8 r;
  r[0] = (short)f2b(a.x); r[1] = (short)f2b(a.y);
  r[2] = (short)f2b(a.z); r[3] = (short)f2b(a.w);
  r[4] = (short)f2b(b.x); r[5] = (short)f2b(b.y);
  r[6] = (short)f2b(b.z); r[7] = (short)f2b(b.w);
  return r;
}

// ---------------- gating (fp32, exact argmax) + x -> bf16 cast ----------------
__global__ __launch_bounds__(256) void gate_kernel(
    const float* __restrict__ x, const float* __restrict__ gw,
    float* __restrict__ probs, int* __restrict__ tok_e,
    float* __restrict__ tok_g, int* __restrict__ cnt,
    ushort* __restrict__ xb) {
  int token = (blockIdx.x * blockDim.x + threadIdx.x) >> 6;
  int lane = threadIdx.x & 63;
  if (token >= N_TOKENS) return;
  const float* xr = x + (size_t)token * D_MODEL;
  float xv[16];
#pragma unroll
  for (int i = 0; i < 16; ++i) xv[i] = xr[lane + 64 * i];
  ushort* xo = xb + (size_t)token * D_MODEL;
#pragma unroll
  for (int i = 0; i < 16; ++i) xo[lane + 64 * i] = f2b(xv[i]);
  float logit[N_EXPERTS];
#pragma unroll
  for (int e = 0; e < N_EXPERTS; ++e) {
    const float* g = gw + e * D_MODEL;
    float s = 0.f;
#pragma unroll
    for (int i = 0; i < 16; ++i) s = fmaf(xv[i], g[lane + 64 * i], s);
#pragma unroll
    for (int m = 32; m; m >>= 1) s += __shfl_xor(s, m, 64);
    logit[e] = s;
  }
  if (lane == 0) {
    float mx = logit[0]; int arg = 0;
#pragma unroll
    for (int e = 1; e < N_EXPERTS; ++e)
      if (logit[e] > mx) { mx = logit[e]; arg = e; }
    float pe[N_EXPERTS]; float den = 0.f;
#pragma unroll
    for (int e = 0; e < N_EXPERTS; ++e) { pe[e] = __expf(logit[e] - mx); den += pe[e]; }
    float inv = 1.f / den;
#pragma unroll
    for (int e = 0; e < N_EXPERTS; ++e) probs[token * N_EXPERTS + e] = pe[e] * inv;
    tok_e[token] = arg;
    tok_g[token] = pe[arg] * inv;
    atomicAdd(&cnt[arg], 1);
  }
}

__global__ __launch_bounds__(256) void imp_kernel(
    const float* __restrict__ probs, float* __restrict__ simp) {
  int row = blockIdx.x * 256 + threadIdx.x;
  const float4* p = (const float4*)(probs + (size_t)row * N_EXPERTS);
  float4 a = p[0], b = p[1];
  float v[8] = {a.x, a.y, a.z, a.w, b.x, b.y, b.z, b.w};
#pragma unroll
  for (int m = 32; m; m >>= 1)
#pragma unroll
    for (int i = 0; i < 8; ++i) v[i] += __shfl_xor(v[i], m, 64);
  if ((threadIdx.x & 63) == 0)
#pragma unroll
    for (int i = 0; i < 8; ++i) atomicAdd(&simp[i], v[i]);
}

__global__ void plan_kernel(
    const int* __restrict__ cnt, const float* __restrict__ simp,
    int* __restrict__ offs, int* __restrict__ ntiles,
    int* __restrict__ tile_e, int* __restrict__ tile_r0,
    float* __restrict__ aux_out) {
  if (threadIdx.x == 0 && blockIdx.x == 0) {
    int o = 0, nt = 0; float aux = 0.f;
    for (int e = 0; e < N_EXPERTS; ++e) {
      offs[e] = o;
      int c = cnt[e];
      int m = (c + M_TILE - 1) / M_TILE;
      for (int i = 0; i < m; ++i) { tile_e[nt] = e; tile_r0[nt] = i * M_TILE; ++nt; }
      aux += (float)c * simp[e];
      o += c;
    }
    offs[N_EXPERTS] = o;
    *ntiles = nt;
    *aux_out = aux * (1.f / ((float)N_TOKENS * (float)N_TOKENS)) * N_EXPERTS * 0.01f;
  }
}

__global__ __launch_bounds__(256) void scatter_kernel(
    const int* __restrict__ tok_e, int* __restrict__ cursor,
    const int* __restrict__ offs, int* __restrict__ bucket) {
  int n = blockIdx.x * blockDim.x + threadIdx.x;
  if (n >= N_TOKENS) return;
  int e = tok_e[n];
  int p = atomicAdd(&cursor[e], 1);
  bucket[offs[e] + p] = n;
}

// ---- GEMM1: 128x128 tile, 512 thr, wave-split: waves 0-3 U(w1), 4-7 V(w3) ----
// Single-buffer 2-barrier loop (m97 structure). A bf16 via global_load_lds;
// B fp32 on-the-fly cvt. Epilogue: V passed through LDS in fp32 (2 half-phases),
// U-waves compute silu(u)*v -> H bf16. Numerics identical to round-2 path.
__global__ __launch_bounds__(512, 4) void gemm1_kernel(
    const ushort* __restrict__ xb, const float* __restrict__ w1,
    const float* __restrict__ w3, const int* __restrict__ ntiles,
    const int* __restrict__ tile_e, const int* __restrict__ tile_r0,
    const int* __restrict__ offs, const int* __restrict__ bucket,
    ushort* __restrict__ H) {
  int tile = blockIdx.y;
  if (tile >= *ntiles) return;
  int e = tile_e[tile], r0 = tile_r0[tile];
  int base = offs[e], cnt = offs[e + 1] - base;
  int f0 = blockIdx.x * 128;

  __shared__ ushort SM[3 * 8192];   // As | B1s | B3s, each 128x64 bf16 (48 KB)
  ushort* As  = SM;
  ushort* B1s = SM + 8192;
  ushort* B3s = SM + 16384;

  int tid = threadIdx.x;
  int w = tid >> 6, lane = tid & 63;
  int uv = w >> 2, sub = w & 3;
  int wm = sub >> 1, wn = sub & 1;

  // A staging: 2 issues/thread; wave w covers rows {c*64 + w*8 .. +7}
  const ushort* aptr[2];
#pragma unroll
  for (int c = 0; c < 2; ++c) {
    int r = c * 64 + w * 8 + (lane >> 3);
    int rr = min(r0 + r, cnt - 1);
    aptr[c] = xb + (size_t)bucket[base + rr] * D_MODEL + (lane & 7) * 8;
  }
  // B staging: row rb (f), cols qb*16..+15
  int rb = tid >> 2, qb = tid & 3;
  const float4* p1 = (const float4*)(w1 + ((size_t)e * EXPERT_DIM + f0 + rb) * D_MODEL + qb * 16);
  const float4* p3 = (const float4*)(w3 + ((size_t)e * EXPERT_DIM + f0 + rb) * D_MODEL + qb * 16);
  int wslot = rb * 64 + qb * 16;

  const ushort* Bsel = uv ? B3s : B1s;

  f32x4 acc[4][4];
#pragma unroll
  for (int i = 0; i < 4; ++i)
#pragma unroll
    for (int j = 0; j < 4; ++j) acc[i][j] = (f32x4)0.f;

  for (int k = 0; k < 16; ++k) {
    GLOAD_LDS16(aptr[0] + k * 64, &As[(w * 8) * 64]);
    GLOAD_LDS16(aptr[1] + k * 64, &As[(64 + w * 8) * 64]);
    {
      const float4* q1 = p1 + k * 16;
      float4 a0 = q1[0], a1 = q1[1], a2 = q1[2], a3 = q1[3];
      *(short8*)&B1s[wslot] = pack8(a0, a1);
      *(short8*)&B1s[wslot + 8] = pack8(a2, a3);
      const float4* q3 = p3 + k * 16;
      float4 b0 = q3[0], b1 = q3[1], b2 = q3[2], b3 = q3[3];
      *(short8*)&B3s[wslot] = pack8(b0, b1);
      *(short8*)&B3s[wslot + 8] = pack8(b2, b3);
    }
    __syncthreads();
#pragma unroll
    for (int ks = 0; ks < 2; ++ks) {
      int ko = ks * 32 + (lane >> 4) * 8;
      short8 af[4], bf[4];
#pragma unroll
      for (int i = 0; i < 4; ++i)
        af[i] = *(const short8*)&As[(wm * 64 + i * 16 + (lane & 15)) * 64 + ko];
#pragma unroll
      for (int j = 0; j < 4; ++j)
        bf[j] = *(const short8*)&Bsel[(wn * 64 + j * 16 + (lane & 15)) * 64 + ko];
#pragma unroll
      for (int i = 0; i < 4; ++i)
#pragma unroll
        for (int j = 0; j < 4; ++j)
          acc[i][j] = __builtin_amdgcn_mfma_f32_16x16x32_bf16(af[i], bf[j], acc[i][j], 0, 0, 0);
    }
    __syncthreads();
  }

  // epilogue: exchange V (fp32) through LDS in two 64-col half-phases
  float* Vbuf = (float*)SM;   // 128 rows x 64 cols f32 = 32 KB
#pragma unroll
  for (int h = 0; h < 2; ++h) {
    __syncthreads();
    if (uv == 1 && wn == h) {
#pragma unroll
      for (int i = 0; i < 4; ++i)
#pragma unroll
        for (int j = 0; j < 4; ++j)
#pragma unroll
          for (int q = 0; q < 4; ++q) {
            int r = wm * 64 + i * 16 + (lane >> 4) * 4 + q;
            Vbuf[r * 64 + j * 16 + (lane & 15)] = acc[i][j][q];
          }
    }
    __syncthreads();
    if (uv == 0 && wn == h) {
#pragma unroll
      for (int i = 0; i < 4; ++i)
#pragma unroll
        for (int q = 0; q < 4; ++q) {
          int r = wm * 64 + i * 16 + (lane >> 4) * 4 + q;
          if (r0 + r < cnt) {
            size_t rowb = (size_t)(base + r0 + r) * EXPERT_DIM + f0 + h * 64;
#pragma unroll
            for (int j = 0; j < 4; ++j) {
              float vv = Vbuf[r * 64 + j * 16 + (lane & 15)];
              float uu = acc[i][j][q];
              float hh = uu / (1.f + __expf(-uu)) * vv;
              H[rowb + j * 16 + (lane & 15)] = f2b(hh);
            }
          }
        }
    }
  }
}

// ---- GEMM2: 128x128 tile, 256 thr (m97 shape), split-K=4 -> fp32 partials ----
__global__ __launch_bounds__(256) void gemm2_kernel(
    const ushort* __restrict__ H, const float* __restrict__ w2,
    const int* __restrict__ ntiles, const int* __restrict__ tile_e,
    const int* __restrict__ tile_r0, const int* __restrict__ offs,
    const int* __restrict__ bucket, float* __restrict__ P) {
  int tile = blockIdx.y;
  if (tile >= *ntiles) return;
  int kz = blockIdx.z;
  int e = tile_e[tile], r0 = tile_r0[tile];
  int base = offs[e], cnt = offs[e + 1] - base;
  int d0 = blockIdx.x * 128;

  __shared__ ushort As[8192];   // 128 x 64 bf16
  __shared__ ushort Bs[8192];   // 128 x 64 bf16

  int tid = threadIdx.x;
  int w = tid >> 6, lane = tid & 63;
  int wm = w >> 1, wn = w & 1;

  const ushort* aptr[4];
#pragma unroll
  for (int c = 0; c < 4; ++c) {
    int r = c * 32 + w * 8 + (lane >> 3);
    int rr = min(r0 + r, cnt - 1);
    aptr[c] = H + (size_t)(base + rr) * EXPERT_DIM + kz * (EXPERT_DIM / KSPLIT) + (lane & 7) * 8;
  }
  int rb = tid >> 1, qb = tid & 1;
  const float4* p2 = (const float4*)(w2 + ((size_t)e * D_MODEL + d0 + rb) * EXPERT_DIM +
                                     kz * (EXPERT_DIM / KSPLIT) + qb * 32);
  int wslot = rb * 64 + qb * 32;

  f32x4 acc[4][4];
#pragma unroll
  for (int i = 0; i < 4; ++i)
#pragma unroll
    for (int j = 0; j < 4; ++j) acc[i][j] = (f32x4)0.f;

  for (int k = 0; k < 16; ++k) {
#pragma unroll
    for (int c = 0; c < 4; ++c)
      GLOAD_LDS16(aptr[c] + k * 64, &As[(c * 32 + w * 8) * 64]);
    {
      const float4* q = p2 + k * 16;
      float4 t0 = q[0], t1 = q[1], t2 = q[2], t3 = q[3];
      float4 t4 = q[4], t5 = q[5], t6 = q[6], t7 = q[7];
      ushort* d = &Bs[wslot];
      *(short8*)d        = pack8(t0, t1);
      *(short8*)(d + 8)  = pack8(t2, t3);
      *(short8*)(d + 16) = pack8(t4, t5);
      *(short8*)(d + 24) = pack8(t6, t7);
    }
    __syncthreads();
#pragma unroll
    for (int ks = 0; ks < 2; ++ks) {
      int ko = ks * 32 + (lane >> 4) * 8;
      short8 af[4], bf[4];
#pragma unroll
      for (int i = 0; i < 4; ++i)
        af[i] = *(const short8*)&As[(wm * 64 + i * 16 + (lane & 15)) * 64 + ko];
#pragma unroll
      for (int j = 0; j < 4; ++j)
        bf[j] = *(const short8*)&Bs[(wn * 64 + j * 16 + (lane & 15)) * 64 + ko];
#pragma unroll
      for (int i = 0; i < 4; ++i)
#pragma unroll
        for (int j = 0; j < 4; ++j)
          acc[i][j] = __builtin_amdgcn_mfma_f32_16x16x32_bf16(af[i], bf[j], acc[i][j], 0, 0, 0);
    }
    __syncthreads();
  }

#pragma unroll
  for (int i = 0; i < 4; ++i)
#pragma unroll
    for (int q = 0; q < 4; ++q) {
      int r = wm * 64 + i * 16 + (lane >> 4) * 4 + q;
      if (r0 + r < cnt) {
        float* pp = P + ((size_t)kz * N_TOKENS + base + r0 + r) * D_MODEL + d0 + wn * 64;
#pragma unroll
        for (int j = 0; j < 4; ++j)
          pp[j * 16 + (lane & 15)] = acc[i][j][q];
      }
    }
}

// ---- reduce: out[tok] = (sum_kz P[kz][pos]) * gate ----
__global__ __launch_bounds__(256) void reduce_kernel(
    const float* __restrict__ P, const int* __restrict__ bucket,
    const float* __restrict__ tok_g, float* __restrict__ out) {
  int gid = blockIdx.x * 256 + threadIdx.x;
  int pos = gid >> 8;                // 256 float4 per row
  int dv = (gid & 255) * 4;
  int tok = bucket[pos];
  float g = tok_g[tok];
  const float* b = P + (size_t)pos * D_MODEL + dv;
  float4 s = *(const float4*)b;
#pragma unroll
  for (int kz = 1; kz < KSPLIT; ++kz) {
    float4 t = *(const float4*)(b + (size_t)kz * N_TOKENS * D_MODEL);
    s.x += t.x; s.y += t.y; s.z += t.z; s.w += t.w;
  }
  float4 r = make_float4(s.x * g, s.y * g, s.z * g, s.w * g);
  *(float4*)(out + (size_t)tok * D_MODEL + dv) = r;
}

extern "C" void kernel_launch(void* const* d_in, const int* in_sizes, int n_in,
                              void* d_out, int out_size, void* d_ws, size_t ws_size,
                              hipStream_t stream) {
  const float* x  = (const float*)d_in[0];
  const float* gw = (const float*)d_in[1];
  const float* w1 = (const float*)d_in[2];
  const float* w2 = (const float*)d_in[3];
  const float* w3 = (const float*)d_in[4];
  float* out = (float*)d_out;
  char* ws = (char*)d_ws;

  float* probs = (float*)(ws + OFF_PROBS);
  int* tok_e   = (int*)(ws + OFF_EXP);
  float* tok_g = (float*)(ws + OFF_GATE);
  int* cnt     = (int*)(ws + OFF_CNT);
  int* cur     = (int*)(ws + OFF_CUR);
  float* simp  = (float*)(ws + OFF_SIMP);
  int* offs    = (int*)(ws + OFF_OFFS);
  int* ntiles  = (int*)(ws + OFF_NT);
  int* tile_e  = (int*)(ws + OFF_TE);
  int* tile_r0 = (int*)(ws + OFF_TR);
  int* bucket  = (int*)(ws + OFF_BUCKET);
  ushort* xb   = (ushort*)(ws + OFF_XB);
  ushort* H    = (ushort*)(ws + OFF_H);
  float* P     = (float*)(ws + OFF_P);

  hipMemsetAsync(ws + OFF_CNT, 0, 96, stream);  // cnt + cursor + simp
  gate_kernel<<<N_TOKENS / 4, 256, 0, stream>>>(x, gw, probs, tok_e, tok_g, cnt, xb);
  imp_kernel<<<N_TOKENS / 256, 256, 0, stream>>>(probs, simp);
  plan_kernel<<<1, 64, 0, stream>>>(cnt, simp, offs, ntiles, tile_e, tile_r0,
                                    out + (size_t)N_TOKENS * D_MODEL);
  scatter_kernel<<<N_TOKENS / 256, 256, 0, stream>>>(tok_e, cur, offs, bucket);
  gemm1_kernel<<<dim3(EXPERT_DIM / 128, MAX_TILES), 512, 0, stream>>>(
      xb, w1, w3, ntiles, tile_e, tile_r0, offs, bucket, H);
  gemm2_kernel<<<dim3(D_MODEL / 128, MAX_TILES, KSPLIT), 256, 0, stream>>>(
      H, w2, ntiles, tile_e, tile_r0, offs, bucket, P);
  reduce_kernel<<<N_TOKENS * D_MODEL / 4 / 256, 256, 0, stream>>>(P, bucket, tok_g, out);
}

// Round 6
// 437.984 us; speedup vs baseline: 1.0369x; 1.0369x over previous
//
#include <hip/hip_runtime.h>
#include <hip/hip_bf16.h>
#include <math.h>

#define D_MODEL    1024
#define EXPERT_DIM 4096
#define N_EXPERTS  8
#define N_TOKENS   4096
#define M_TILE     128
#define MAX_TILES  40
#define KSPLIT     4

typedef __attribute__((ext_vector_type(8))) short short8;
typedef __attribute__((ext_vector_type(4))) float f32x4;

// workspace byte offsets (ws_size proven >= 176 MB in R3)
#define OFF_PROBS   0u
#define OFF_EXP     131072u
#define OFF_GATE    147456u
#define OFF_CNT     163840u     // 8 i32
#define OFF_CUR     163872u     // 8 i32
#define OFF_SIMP    163904u     // 8 f32
#define OFF_OFFS    163936u     // 9 i32
#define OFF_NT      163976u     // 1 i32
#define OFF_TE      164096u     // 40 i32
#define OFF_TR      164352u     // 40 i32
#define OFF_BUCKET  164608u     // 4096 i32
#define OFF_XB      262144u     // 4096*1024 bf16 = 8 MiB
#define OFF_H       8650752u    // 4096*4096 bf16 = 32 MiB
#define OFF_P       42205184u   // KSPLIT*4096*1024 f32 = 64 MiB (ends ~106 MiB)

#define GLOAD_LDS16(gp, lp) \
  __builtin_amdgcn_global_load_lds((const __attribute__((address_space(1))) void*)(gp), \
                                   (__attribute__((address_space(3))) void*)(lp), 16, 0, 0)

static __device__ __forceinline__ ushort f2b(float f) {
  union { __hip_bfloat16 h; ushort u; } c;
  c.h = __float2bfloat16(f);
  return c.u;
}

static __device__ __forceinline__ short8 cvt8(f32x4 a, f32x4 b) {
  short8 r;
  r[0] = (short)f2b(a[0]); r[1] = (short)f2b(a[1]);
  r[2] = (short)f2b(a[2]); r[3] = (short)f2b(a[3]);
  r[4] = (short)f2b(b[0]); r[5] = (short)f2b(b[1]);
  r[6] = (short)f2b(b[2]); r[7] = (short)f2b(b[3]);
  return r;
}

// ---------------- gating (fp32, exact argmax) + x -> bf16 cast ----------------
__global__ __launch_bounds__(256) void gate_kernel(
    const float* __restrict__ x, const float* __restrict__ gw,
    float* __restrict__ probs, int* __restrict__ tok_e,
    float* __restrict__ tok_g, int* __restrict__ cnt,
    ushort* __restrict__ xb) {
  int token = (blockIdx.x * blockDim.x + threadIdx.x) >> 6;
  int lane = threadIdx.x & 63;
  if (token >= N_TOKENS) return;
  const float* xr = x + (size_t)token * D_MODEL;
  float xv[16];
#pragma unroll
  for (int i = 0; i < 16; ++i) xv[i] = xr[lane + 64 * i];
  ushort* xo = xb + (size_t)token * D_MODEL;
#pragma unroll
  for (int i = 0; i < 16; ++i) xo[lane + 64 * i] = f2b(xv[i]);
  float logit[N_EXPERTS];
#pragma unroll
  for (int e = 0; e < N_EXPERTS; ++e) {
    const float* g = gw + e * D_MODEL;
    float s = 0.f;
#pragma unroll
    for (int i = 0; i < 16; ++i) s = fmaf(xv[i], g[lane + 64 * i], s);
#pragma unroll
    for (int m = 32; m; m >>= 1) s += __shfl_xor(s, m, 64);
    logit[e] = s;
  }
  if (lane == 0) {
    float mx = logit[0]; int arg = 0;
#pragma unroll
    for (int e = 1; e < N_EXPERTS; ++e)
      if (logit[e] > mx) { mx = logit[e]; arg = e; }
    float pe[N_EXPERTS]; float den = 0.f;
#pragma unroll
    for (int e = 0; e < N_EXPERTS; ++e) { pe[e] = __expf(logit[e] - mx); den += pe[e]; }
    float inv = 1.f / den;
#pragma unroll
    for (int e = 0; e < N_EXPERTS; ++e) probs[token * N_EXPERTS + e] = pe[e] * inv;
    tok_e[token] = arg;
    tok_g[token] = pe[arg] * inv;
    atomicAdd(&cnt[arg], 1);
  }
}

__global__ __launch_bounds__(256) void imp_kernel(
    const float* __restrict__ probs, float* __restrict__ simp) {
  int row = blockIdx.x * 256 + threadIdx.x;
  const float4* p = (const float4*)(probs + (size_t)row * N_EXPERTS);
  float4 a = p[0], b = p[1];
  float v[8] = {a.x, a.y, a.z, a.w, b.x, b.y, b.z, b.w};
#pragma unroll
  for (int m = 32; m; m >>= 1)
#pragma unroll
    for (int i = 0; i < 8; ++i) v[i] += __shfl_xor(v[i], m, 64);
  if ((threadIdx.x & 63) == 0)
#pragma unroll
    for (int i = 0; i < 8; ++i) atomicAdd(&simp[i], v[i]);
}

__global__ void plan_kernel(
    const int* __restrict__ cnt, const float* __restrict__ simp,
    int* __restrict__ offs, int* __restrict__ ntiles,
    int* __restrict__ tile_e, int* __restrict__ tile_r0,
    float* __restrict__ aux_out) {
  if (threadIdx.x == 0 && blockIdx.x == 0) {
    int o = 0, nt = 0; float aux = 0.f;
    for (int e = 0; e < N_EXPERTS; ++e) {
      offs[e] = o;
      int c = cnt[e];
      int m = (c + M_TILE - 1) / M_TILE;
      for (int i = 0; i < m; ++i) { tile_e[nt] = e; tile_r0[nt] = i * M_TILE; ++nt; }
      aux += (float)c * simp[e];
      o += c;
    }
    offs[N_EXPERTS] = o;
    *ntiles = nt;
    *aux_out = aux * (1.f / ((float)N_TOKENS * (float)N_TOKENS)) * N_EXPERTS * 0.01f;
  }
}

__global__ __launch_bounds__(256) void scatter_kernel(
    const int* __restrict__ tok_e, int* __restrict__ cursor,
    const int* __restrict__ offs, int* __restrict__ bucket) {
  int n = blockIdx.x * blockDim.x + threadIdx.x;
  if (n >= N_TOKENS) return;
  int e = tok_e[n];
  int p = atomicAdd(&cursor[e], 1);
  bucket[offs[e] + p] = n;
}

// ---- GEMM1: 128x128 tile, 256 thr, dual acc (U,V). A bf16 + B fp32 both via
// global_load_lds (async); fp32->bf16 cvt in MFMA phase. XOR-swizzled LDS
// (linear dest + pre-swizzled global source + swizzled read, rule #21).
// XCD-chunked 1-D grid, m-fastest (B-panel L2 reuse, T1).
__global__ __launch_bounds__(256) void gemm1_kernel(
    const ushort* __restrict__ xb, const float* __restrict__ w1,
    const float* __restrict__ w3, const int* __restrict__ ntiles,
    const int* __restrict__ tile_e, const int* __restrict__ tile_r0,
    const int* __restrict__ offs, const int* __restrict__ bucket,
    ushort* __restrict__ H) {
  // nwg = 32*40 = 1280; xcd chunk = 160 = 4 f-panels x 40 m-tiles
  int bid = blockIdx.x;
  int wgid = (bid & 7) * 160 + (bid >> 3);
  int fi = wgid / MAX_TILES;
  int tile = wgid % MAX_TILES;
  if (tile >= *ntiles) return;
  int e = tile_e[tile], r0 = tile_r0[tile];
  int base = offs[e], cnt = offs[e + 1] - base;
  int f0 = fi * 128;

  __shared__ ushort As[128 * 64];   // 16 KB, bf16, swizzled elem ^ ((row&7)<<3)
  __shared__ float B1f[128 * 64];   // 32 KB, fp32, swizzled elem ^ ((row&7)<<2)
  __shared__ float B3f[128 * 64];   // 32 KB

  int tid = threadIdx.x;
  int w = tid >> 6, l = tid & 63;
  int wm = w >> 1, wn = w & 1;

  // A staging ptrs: call c covers rows c*32 + w*8 + (l>>3); source col
  // pre-swizzled: ((l&7) ^ (l>>3)) * 8  (row&7 == l>>3)
  const ushort* aptr[4];
#pragma unroll
  for (int c = 0; c < 4; ++c) {
    int r = c * 32 + w * 8 + (l >> 3);
    int rr = min(r0 + r, cnt - 1);
    aptr[c] = xb + (size_t)bucket[base + rr] * D_MODEL + ((l & 7) ^ (l >> 3)) * 8;
  }
  // B staging: call c covers rows c*16 + w*4 + (l>>4); 16 lanes cover one
  // 64-fp32 row; source col pre-swizzled: ((l&15) ^ (row&7)) * 4
  int brow = w * 4 + (l >> 4);
  int bcol = ((l & 15) ^ (brow & 7)) * 4;
  const float* b1p = w1 + ((size_t)e * EXPERT_DIM + f0 + brow) * D_MODEL + bcol;
  const float* b3p = w3 + ((size_t)e * EXPERT_DIM + f0 + brow) * D_MODEL + bcol;

  f32x4 accU[4][4], accV[4][4];
#pragma unroll
  for (int i = 0; i < 4; ++i)
#pragma unroll
    for (int j = 0; j < 4; ++j) { accU[i][j] = (f32x4)0.f; accV[i][j] = (f32x4)0.f; }

  for (int k = 0; k < 16; ++k) {
    int k0 = k * 64;
#pragma unroll
    for (int c = 0; c < 4; ++c)
      GLOAD_LDS16(aptr[c] + k0, &As[(c * 32 + w * 8) * 64]);
#pragma unroll
    for (int c = 0; c < 8; ++c) {
      GLOAD_LDS16(b1p + (size_t)c * 16 * D_MODEL + k0, &B1f[(c * 16 + w * 4) * 64]);
      GLOAD_LDS16(b3p + (size_t)c * 16 * D_MODEL + k0, &B3f[(c * 16 + w * 4) * 64]);
    }
    __syncthreads();
#pragma unroll
    for (int ks = 0; ks < 2; ++ks) {
      int acol = (ks * 32 + (l >> 4) * 8) ^ ((l & 7) << 3);
      short8 af[4];
#pragma unroll
      for (int i = 0; i < 4; ++i)
        af[i] = *(const short8*)&As[(wm * 64 + i * 16 + (l & 15)) * 64 + acol];
      int boff0 = (ks * 32 + (l >> 4) * 8 + 0) ^ ((l & 7) << 2);
      int boff1 = (ks * 32 + (l >> 4) * 8 + 4) ^ ((l & 7) << 2);
#pragma unroll
      for (int j = 0; j < 4; ++j) {
        int br = (wn * 64 + j * 16 + (l & 15)) * 64;
        short8 bb1 = cvt8(*(const f32x4*)&B1f[br + boff0], *(const f32x4*)&B1f[br + boff1]);
#pragma unroll
        for (int i = 0; i < 4; ++i)
          accU[i][j] = __builtin_amdgcn_mfma_f32_16x16x32_bf16(af[i], bb1, accU[i][j], 0, 0, 0);
        short8 bb3 = cvt8(*(const f32x4*)&B3f[br + boff0], *(const f32x4*)&B3f[br + boff1]);
#pragma unroll
        for (int i = 0; i < 4; ++i)
          accV[i][j] = __builtin_amdgcn_mfma_f32_16x16x32_bf16(af[i], bb3, accV[i][j], 0, 0, 0);
      }
    }
    __syncthreads();
  }

  // epilogue: h = silu(u)*v -> bf16 H (U and V live in the same thread)
#pragma unroll
  for (int i = 0; i < 4; ++i)
#pragma unroll
    for (int q = 0; q < 4; ++q) {
      int m_loc = wm * 64 + i * 16 + (l >> 4) * 4 + q;
      if (r0 + m_loc < cnt) {
        size_t rowb = (size_t)(base + r0 + m_loc) * EXPERT_DIM + f0 + wn * 64 + (l & 15);
#pragma unroll
        for (int j = 0; j < 4; ++j) {
          float uu = accU[i][j][q], vv = accV[i][j][q];
          float hh = uu / (1.f + __expf(-uu)) * vv;
          H[rowb + j * 16] = f2b(hh);
        }
      }
    }
}

// ---- GEMM2: 128x128 tile, split-K=4, same staging scheme -> fp32 partials ----
__global__ __launch_bounds__(256) void gemm2_kernel(
    const ushort* __restrict__ H, const float* __restrict__ w2,
    const int* __restrict__ ntiles, const int* __restrict__ tile_e,
    const int* __restrict__ tile_r0, const int* __restrict__ offs,
    float* __restrict__ P) {
  // nwg = 8*40*4 = 1280; xcd chunk = 160 = one d-panel (4 kz x 40 m)
  int bid = blockIdx.x;
  int wgid = (bid & 7) * 160 + (bid >> 3);
  int di = wgid / (MAX_TILES * KSPLIT);
  int rest = wgid % (MAX_TILES * KSPLIT);
  int kz = rest / MAX_TILES;
  int tile = rest % MAX_TILES;
  if (tile >= *ntiles) return;
  int e = tile_e[tile], r0 = tile_r0[tile];
  int base = offs[e], cnt = offs[e + 1] - base;
  int d0 = di * 128;

  __shared__ ushort As[128 * 64];   // 16 KB
  __shared__ float Bf[128 * 64];    // 32 KB

  int tid = threadIdx.x;
  int w = tid >> 6, l = tid & 63;
  int wm = w >> 1, wn = w & 1;

  const ushort* aptr[4];
#pragma unroll
  for (int c = 0; c < 4; ++c) {
    int r = c * 32 + w * 8 + (l >> 3);
    int rr = min(r0 + r, cnt - 1);
    aptr[c] = H + (size_t)(base + rr) * EXPERT_DIM + kz * (EXPERT_DIM / KSPLIT) +
              ((l & 7) ^ (l >> 3)) * 8;
  }
  int brow = w * 4 + (l >> 4);
  int bcol = ((l & 15) ^ (brow & 7)) * 4;
  const float* b2p = w2 + ((size_t)e * D_MODEL + d0 + brow) * EXPERT_DIM +
                     kz * (EXPERT_DIM / KSPLIT) + bcol;

  f32x4 acc[4][4];
#pragma unroll
  for (int i = 0; i < 4; ++i)
#pragma unroll
    for (int j = 0; j < 4; ++j) acc[i][j] = (f32x4)0.f;

  for (int k = 0; k < 16; ++k) {
    int k0 = k * 64;
#pragma unroll
    for (int c = 0; c < 4; ++c)
      GLOAD_LDS16(aptr[c] + k0, &As[(c * 32 + w * 8) * 64]);
#pragma unroll
    for (int c = 0; c < 8; ++c)
      GLOAD_LDS16(b2p + (size_t)c * 16 * EXPERT_DIM + k0, &Bf[(c * 16 + w * 4) * 64]);
    __syncthreads();
#pragma unroll
    for (int ks = 0; ks < 2; ++ks) {
      int acol = (ks * 32 + (l >> 4) * 8) ^ ((l & 7) << 3);
      short8 af[4];
#pragma unroll
      for (int i = 0; i < 4; ++i)
        af[i] = *(const short8*)&As[(wm * 64 + i * 16 + (l & 15)) * 64 + acol];
      int boff0 = (ks * 32 + (l >> 4) * 8 + 0) ^ ((l & 7) << 2);
      int boff1 = (ks * 32 + (l >> 4) * 8 + 4) ^ ((l & 7) << 2);
#pragma unroll
      for (int j = 0; j < 4; ++j) {
        int br = (wn * 64 + j * 16 + (l & 15)) * 64;
        short8 bb = cvt8(*(const f32x4*)&Bf[br + boff0], *(const f32x4*)&Bf[br + boff1]);
#pragma unroll
        for (int i = 0; i < 4; ++i)
          acc[i][j] = __builtin_amdgcn_mfma_f32_16x16x32_bf16(af[i], bb, acc[i][j], 0, 0, 0);
      }
    }
    __syncthreads();
  }

#pragma unroll
  for (int i = 0; i < 4; ++i)
#pragma unroll
    for (int q = 0; q < 4; ++q) {
      int r = wm * 64 + i * 16 + (l >> 4) * 4 + q;
      if (r0 + r < cnt) {
        float* pp = P + ((size_t)kz * N_TOKENS + base + r0 + r) * D_MODEL + d0 + wn * 64;
#pragma unroll
        for (int j = 0; j < 4; ++j)
          pp[j * 16 + (l & 15)] = acc[i][j][q];
      }
    }
}

// ---- reduce: out[tok] = (sum_kz P[kz][pos]) * gate ----
__global__ __launch_bounds__(256) void reduce_kernel(
    const float* __restrict__ P, const int* __restrict__ bucket,
    const float* __restrict__ tok_g, float* __restrict__ out) {
  int gid = blockIdx.x * 256 + threadIdx.x;
  int pos = gid >> 8;
  int dv = (gid & 255) * 4;
  int tok = bucket[pos];
  float g = tok_g[tok];
  const float* b = P + (size_t)pos * D_MODEL + dv;
  float4 s = *(const float4*)b;
#pragma unroll
  for (int kz = 1; kz < KSPLIT; ++kz) {
    float4 t = *(const float4*)(b + (size_t)kz * N_TOKENS * D_MODEL);
    s.x += t.x; s.y += t.y; s.z += t.z; s.w += t.w;
  }
  float4 r = make_float4(s.x * g, s.y * g, s.z * g, s.w * g);
  *(float4*)(out + (size_t)tok * D_MODEL + dv) = r;
}

extern "C" void kernel_launch(void* const* d_in, const int* in_sizes, int n_in,
                              void* d_out, int out_size, void* d_ws, size_t ws_size,
                              hipStream_t stream) {
  const float* x  = (const float*)d_in[0];
  const float* gw = (const float*)d_in[1];
  const float* w1 = (const float*)d_in[2];
  const float* w2 = (const float*)d_in[3];
  const float* w3 = (const float*)d_in[4];
  float* out = (float*)d_out;
  char* ws = (char*)d_ws;

  float* probs = (float*)(ws + OFF_PROBS);
  int* tok_e   = (int*)(ws + OFF_EXP);
  float* tok_g = (float*)(ws + OFF_GATE);
  int* cnt     = (int*)(ws + OFF_CNT);
  int* cur     = (int*)(ws + OFF_CUR);
  float* simp  = (float*)(ws + OFF_SIMP);
  int* offs    = (int*)(ws + OFF_OFFS);
  int* ntiles  = (int*)(ws + OFF_NT);
  int* tile_e  = (int*)(ws + OFF_TE);
  int* tile_r0 = (int*)(ws + OFF_TR);
  int* bucket  = (int*)(ws + OFF_BUCKET);
  ushort* xb   = (ushort*)(ws + OFF_XB);
  ushort* H    = (ushort*)(ws + OFF_H);
  float* P     = (float*)(ws + OFF_P);

  hipMemsetAsync(ws + OFF_CNT, 0, 96, stream);  // cnt + cursor + simp
  gate_kernel<<<N_TOKENS / 4, 256, 0, stream>>>(x, gw, probs, tok_e, tok_g, cnt, xb);
  imp_kernel<<<N_TOKENS / 256, 256, 0, stream>>>(probs, simp);
  plan_kernel<<<1, 64, 0, stream>>>(cnt, simp, offs, ntiles, tile_e, tile_r0,
                                    out + (size_t)N_TOKENS * D_MODEL);
  scatter_kernel<<<N_TOKENS / 256, 256, 0, stream>>>(tok_e, cur, offs, bucket);
  gemm1_kernel<<<32 * MAX_TILES, 256, 0, stream>>>(
      xb, w1, w3, ntiles, tile_e, tile_r0, offs, bucket, H);
  gemm2_kernel<<<(D_MODEL / 128) * MAX_TILES * KSPLIT, 256, 0, stream>>>(
      H, w2, ntiles, tile_e, tile_r0, offs, P);
  reduce_kernel<<<N_TOKENS * D_MODEL / 4 / 256, 256, 0, stream>>>(P, bucket, tok_g, out);
}